// Round 8
// baseline (140.790 us; speedup 1.0000x reference)
//
#include <hip/hip_runtime.h>
#include <stdint.h>

#define BATCH 16384
#define MAXA 32
#define FEAT 768
#define HIDDEN 1024

#define KC 24                    // K-chunks of 32 features
#define NT 32                    // N-tiles of 32 hidden cols
#define ASTRIDE 784              // A row stride (768 + 16 pad)
#define AWBYTES (32 * ASTRIDE)   // 25088 B per wave
#define BTILE (KC * 1024)        // 24576 B per N-tile slab

typedef int v4i  __attribute__((ext_vector_type(4)));
typedef int v16i __attribute__((ext_vector_type(16)));

// ---------------------------------------------------------------------------
// Prep: per-h absmax -> scale; quantize SIGNED i8 (-127..127); write directly
// in MFMA B-fragment order:  byte(f,h) -> Bf[(nt*KC+kc)*1024 + l*16 + e]
// where nt=h>>5, kc=f>>5, l=((f>>4)&1)<<5 | (h&31), e=f&15.
// Also zeroes the output accumulator (nn_mfma atomicAdds into d_out).
// ---------------------------------------------------------------------------
__global__ __launch_bounds__(256) void prep_quant(const float* __restrict__ ftw,
                                                  uint8_t* __restrict__ Bf,
                                                  float* __restrict__ scale,
                                                  float* __restrict__ outz) {
  const int h0 = blockIdx.x * 8;
  const int hloc = threadIdx.x >> 5;   // 0..7
  const int l32 = threadIdx.x & 31;    // 0..31
  const int h = h0 + hloc;

  float w[24];
  float amax = 0.f;
  const float* __restrict__ src = ftw + (size_t)h * FEAT;
#pragma unroll
  for (int k = 0; k < 24; ++k) {
    w[k] = src[l32 + 32 * k];
    amax = fmaxf(amax, fabsf(w[k]));
  }
#pragma unroll
  for (int m = 1; m <= 16; m <<= 1)
    amax = fmaxf(amax, __shfl_xor(amax, m, 64));
  amax = fmaxf(amax, 1e-20f);
  if (l32 == 0) scale[h] = amax / 127.f;
  const float inv = 127.f / amax;

  __shared__ __align__(16) uint8_t tile[8][ASTRIDE];  // [hloc][f], 6.1 KB
#pragma unroll
  for (int k = 0; k < 24; ++k) {
    int q = __float2int_rn(w[k] * inv);               // [-127,127] signed
    tile[hloc][l32 + 32 * k] = (uint8_t)(int8_t)q;
  }
  __syncthreads();

  // scatter 16-byte groups into fragment order (16 consecutive f, same h)
  for (int g = threadIdx.x; g < 8 * 48; g += 256) {
    int hl = g / 48, fg = g % 48;
    int kc = fg >> 1, lh = fg & 1;
    int hh = h0 + hl;
    uint4 v = *(const uint4*)&tile[hl][fg * 16];
    size_t daddr = ((size_t)((hh >> 5) * KC + kc) << 10) +
                   (size_t)(((lh << 5) | (hh & 31)) << 4);
    *(uint4*)(Bf + daddr) = v;
  }

  if (threadIdx.x < 128)   // zero the per-row output accumulator (16384 f32)
    outz[blockIdx.x * 128 + threadIdx.x] = 0.f;
}

// ---------------------------------------------------------------------------
// Dense i8 MFMA: out[r] += clip01(Wq·A^T)·out_w. 1 block/CU (256 blocks),
// 4 waves; wave = 32 rows x 1 side. A(0/1) built by LDS scatter (dedupe +
// padding free), lifted to 96 VGPRs; B slabs double-buffered through LDS
// (reg-staged, issue-early/write-late); 24 x mfma_i32_32x32x32_i8 per N-tile;
// per-tile dequant+clip+dot epilogue; 2 atomicAdds per row into d_out.
// ---------------------------------------------------------------------------
__global__ __launch_bounds__(256, 1) void nn_mfma(
    const int* __restrict__ stm, const int* __restrict__ nstm,
    const uint8_t* __restrict__ Bf, const float* __restrict__ scale,
    const float* __restrict__ bias, const float* __restrict__ outw,
    float* __restrict__ outz)
{
  const int tid  = threadIdx.x;
  const int lane = tid & 63;
  const int wid  = tid >> 6;        // 0..3
  const int side = wid & 1;         // 0 = stm, 1 = nstm
  const int rgrp = wid >> 1;        // 0..1
  const int r0   = blockIdx.x * 64 + rgrp * 32;
  const int l31  = lane & 31;
  const int lh   = lane >> 5;

  __shared__ __align__(16) uint8_t Ash[4 * AWBYTES];   // 100352 B
  __shared__ __align__(16) uint8_t Bbuf[2][BTILE];     // 49152 B (total 146 KiB)

  uint8_t* Aw = Ash + wid * AWBYTES;

  // ---- issue B-slab 0 loads early (hide under A build)
  uint4 st[6];
  {
    const uint4* g = (const uint4*)Bf;
#pragma unroll
    for (int s = 0; s < 6; ++s) st[s] = g[s * 256 + tid];
  }

  // ---- zero this wave's A region (25088 B)
  const uint4 z4 = {0u, 0u, 0u, 0u};
#pragma unroll
  for (int it = 0; it < 25; ++it) {
    int off = it * 1024 + lane * 16;
    if (off < AWBYTES) *(uint4*)(Aw + off) = z4;
  }
  // ---- scatter ones: row = 2*i + lh from position l31. Duplicates
  // overwrite (ref .at[].max() semantics); idx<0 skipped.
  const int* __restrict__ isrc = side ? nstm : stm;
#pragma unroll
  for (int i = 0; i < 16; ++i) {
    int row = i * 2 + lh;
    int idx = isrc[(r0 + row) * MAXA + l31];
    if (idx >= 0) Aw[row * ASTRIDE + idx] = 1;
  }
  // ---- lift A fragments: lane supplies A[m=l31][k=lh*16+e], e=0..15
  v4i areg[KC];
#pragma unroll
  for (int kc = 0; kc < KC; ++kc)
    areg[kc] = *(const v4i*)(Aw + l31 * ASTRIDE + kc * 32 + lh * 16);

  // ---- park B-slab 0, make visible
#pragma unroll
  for (int s = 0; s < 6; ++s) ((uint4*)Bbuf[0])[s * 256 + tid] = st[s];
  __syncthreads();

  // ---- A region is dead: reuse front 16 KB for scale/bias/outw
  float* sbo = (float*)Ash;  // [0,1024) scale  [1024,2048) bias  [2048,4096) outw
  {
    const float4* gs = (const float4*)scale;
    const float4* gb = (const float4*)bias;
    const float4* go = (const float4*)outw;
    float4* d = (float4*)sbo;
    d[tid]       = gs[tid];
    d[256 + tid] = gb[tid];
    d[512 + tid] = go[tid];
    d[768 + tid] = go[256 + tid];
  }
  __syncthreads();

  float prow[16];
#pragma unroll
  for (int r = 0; r < 16; ++r) prow[r] = 0.f;

#pragma unroll 1
  for (int nt = 0; nt < NT; ++nt) {
    const int p = nt & 1;
    // issue next slab's global loads (consumed after the compute)
    if (nt + 1 < NT) {
      const uint4* g = (const uint4*)(Bf + (size_t)(nt + 1) * BTILE);
#pragma unroll
      for (int s = 0; s < 6; ++s) st[s] = g[s * 256 + tid];
    }
    // 24-step K chain: C[32 rows x 32 h] in 16 i32/lane
    v16i acc;
#pragma unroll
    for (int r = 0; r < 16; ++r) acc[r] = 0;
    const uint8_t* bp = Bbuf[p];
#pragma unroll
    for (int kc = 0; kc < KC; ++kc) {
      v4i b = *(const v4i*)(bp + kc * 1024 + lane * 16);
      acc = __builtin_amdgcn_mfma_i32_32x32x32_i8(areg[kc], b, acc, 0, 0, 0);
    }
    // epilogue: h = nt*32 + l31 for all 16 regs (C col = lane&31)
    float s  = sbo[nt * 32 + l31];
    float bb = sbo[1024 + nt * 32 + l31];
    float o  = sbo[2048 + side * HIDDEN + nt * 32 + l31];
#pragma unroll
    for (int r = 0; r < 16; ++r) {
      float hv = fminf(fmaxf(fmaf((float)acc[r], s, bb), 0.f), 1.f);
      prow[r] = fmaf(hv, o, prow[r]);
    }
    // park next slab into the released buffer; barrier flips ownership
    if (nt + 1 < NT) {
      uint4* d = (uint4*)Bbuf[p ^ 1];
#pragma unroll
      for (int s2 = 0; s2 < 6; ++s2) d[s2 * 256 + tid] = st[s2];
    }
    __syncthreads();
  }

  // ---- reduce over the 32 h-columns (lanes of each half share row set)
#pragma unroll
  for (int off = 16; off >= 1; off >>= 1)
#pragma unroll
    for (int r = 0; r < 16; ++r) prow[r] += __shfl_xor(prow[r], off, 64);

  if (l31 == 0) {
    // C row = (reg&3) + 8*(reg>>2) + 4*(lane>>5)  [HW-verified 32x32 layout]
#pragma unroll
    for (int r = 0; r < 16; ++r) {
      int row = (r & 3) + 8 * (r >> 2) + 4 * lh;
      atomicAdd(&outz[r0 + row], prow[r]);
    }
  }
}

// ---------------------------------------------------------------------------
// Final: sigmoid in place over the accumulated per-row dot.
// ---------------------------------------------------------------------------
__global__ __launch_bounds__(256) void nn_finish(float* __restrict__ outz,
                                                 const float* __restrict__ outb) {
  const int i = blockIdx.x * 256 + threadIdx.x;
  float y = outz[i] + outb[0];
  outz[i] = 1.f / (1.f + __expf(-y));
}

extern "C" void kernel_launch(void* const* d_in, const int* in_sizes, int n_in,
                              void* d_out, int out_size, void* d_ws, size_t ws_size,
                              hipStream_t stream) {
  const int*   stm  = (const int*)d_in[0];
  const int*   nstm = (const int*)d_in[1];
  const float* ftw  = (const float*)d_in[2];   // (1024, 768) fp32
  const float* ftb  = (const float*)d_in[3];   // (1024,) fp32
  const float* outw = (const float*)d_in[4];   // (2048,) fp32
  const float* outb = (const float*)d_in[5];   // (1,) fp32

  uint8_t* Bf    = (uint8_t*)d_ws;                        // 768 KiB fragments
  float*   scale = (float*)(Bf + (size_t)FEAT * HIDDEN);  // 4 KB
  float*   outz  = (float*)d_out;                         // accumulator + output

  prep_quant<<<HIDDEN / 8, 256, 0, stream>>>(ftw, Bf, scale, outz);
  nn_mfma<<<BATCH / 64, 256, 0, stream>>>(stm, nstm, Bf, scale, ftb, outw, outz);
  nn_finish<<<BATCH / 256, 256, 0, stream>>>(outz, outb);
}

// Round 9
// 138.628 us; speedup vs baseline: 1.0156x; 1.0156x over previous
//
#include <hip/hip_runtime.h>
#include <stdint.h>

#define BATCH 16384
#define MAXA 32
#define FEAT 768
#define HIDDEN 1024

#define KC 24                    // K-chunks of 32 features
#define NTH 16                   // N-tiles per block (half of 32: N-split)
#define ASTRIDE 784              // A row stride (768 + 16 pad)
#define AWBYTES (32 * ASTRIDE)   // 25088 B per tile-map
#define BTILE (KC * 1024)        // 24576 B per N-tile slab

typedef int v4i  __attribute__((ext_vector_type(4)));
typedef int v16i __attribute__((ext_vector_type(16)));

// ---------------------------------------------------------------------------
// Prep: per-h absmax -> scale; quantize SIGNED i8 (-127..127); write directly
// in MFMA B-fragment order:  byte(f,h) -> Bf[(nt*KC+kc)*1024 + l*16 + e]
// where nt=h>>5, kc=f>>5, l=((f>>4)&1)<<5 | (h&31), e=f&15.
// Also zeroes the output accumulator (nn_mfma atomicAdds into d_out).
// ---------------------------------------------------------------------------
__global__ __launch_bounds__(256) void prep_quant(const float* __restrict__ ftw,
                                                  uint8_t* __restrict__ Bf,
                                                  float* __restrict__ scale,
                                                  float* __restrict__ outz) {
  const int h0 = blockIdx.x * 8;
  const int hloc = threadIdx.x >> 5;   // 0..7
  const int l32 = threadIdx.x & 31;    // 0..31
  const int h = h0 + hloc;

  float w[24];
  float amax = 0.f;
  const float* __restrict__ src = ftw + (size_t)h * FEAT;
#pragma unroll
  for (int k = 0; k < 24; ++k) {
    w[k] = src[l32 + 32 * k];
    amax = fmaxf(amax, fabsf(w[k]));
  }
#pragma unroll
  for (int m = 1; m <= 16; m <<= 1)
    amax = fmaxf(amax, __shfl_xor(amax, m, 64));
  amax = fmaxf(amax, 1e-20f);
  if (l32 == 0) scale[h] = amax / 127.f;
  const float inv = 127.f / amax;

  __shared__ __align__(16) uint8_t tile[8][ASTRIDE];  // [hloc][f], 6.1 KB
#pragma unroll
  for (int k = 0; k < 24; ++k) {
    int q = __float2int_rn(w[k] * inv);               // [-127,127] signed
    tile[hloc][l32 + 32 * k] = (uint8_t)(int8_t)q;
  }
  __syncthreads();

  // scatter 16-byte groups into fragment order (16 consecutive f, same h)
  for (int g = threadIdx.x; g < 8 * 48; g += 256) {
    int hl = g / 48, fg = g % 48;
    int kc = fg >> 1, lh = fg & 1;
    int hh = h0 + hl;
    uint4 v = *(const uint4*)&tile[hl][fg * 16];
    size_t daddr = ((size_t)((hh >> 5) * KC + kc) << 10) +
                   (size_t)(((lh << 5) | (hh & 31)) << 4);
    *(uint4*)(Bf + daddr) = v;
  }

  if (threadIdx.x < 128)   // zero the per-row output accumulator (16384 f32)
    outz[blockIdx.x * 128 + threadIdx.x] = 0.f;
}

// ---------------------------------------------------------------------------
// Dense i8 MFMA v2. Grid = 256 (1/CU): block = (128 rows) x (one 512-h
// N-half). 4 waves; wave = 64 rows x 1 side = TWO 32-row A-tiles held in
// 192 VGPRs. Per N-tile: one ds_read_b128 B-fragment feeds 2 independent
// MFMAs (2x dep-chain spacing, halved per-row DS traffic vs v1). B slabs
// double-buffered through LDS (issue-early/write-late). R8 showed 1
// wave/SIMD + 24-deep dependent chain + full-B DS funnel = 79.8us; this
// halves both dominant terms via amortization + ILP rather than TLP.
// ---------------------------------------------------------------------------
__global__ __launch_bounds__(256, 1) void nn_mfma(
    const int* __restrict__ stm, const int* __restrict__ nstm,
    const uint8_t* __restrict__ Bf, const float* __restrict__ scale,
    const float* __restrict__ bias, const float* __restrict__ outw,
    float* __restrict__ outz)
{
  const int tid  = threadIdx.x;
  const int lane = tid & 63;
  const int wid  = tid >> 6;        // 0..3
  const int side = wid & 1;         // 0 = stm, 1 = nstm
  const int rgrp = wid >> 1;        // 0..1
  const int nh   = blockIdx.x & 1;  // N-half (h = nh*512 .. +512)
  const int R    = (blockIdx.x >> 1) * 128;
  const int l31  = lane & 31;
  const int lh   = lane >> 5;

  __shared__ __align__(16) uint8_t Ash[4 * AWBYTES];   // 100352 B
  __shared__ __align__(16) uint8_t Bbuf[2][BTILE];     // 49152 B

  uint8_t* Aw = Ash + wid * AWBYTES;

  // ---- issue first B-slab loads early (hide under A build)
  uint4 st[6];
  {
    const uint4* g = (const uint4*)(Bf + (size_t)(nh * NTH) * BTILE);
#pragma unroll
    for (int s = 0; s < 6; ++s) st[s] = g[s * 256 + tid];
  }

  // ---- build TWO A-tiles sequentially in this wave's private LDS region
  const int* __restrict__ isrc = side ? nstm : stm;
  const uint4 z4 = {0u, 0u, 0u, 0u};
  v4i areg[2][KC];
#pragma unroll
  for (int t = 0; t < 2; ++t) {
    // zero the 25088 B map
#pragma unroll
    for (int it = 0; it < 25; ++it) {
      int off = it * 1024 + lane * 16;
      if (off < AWBYTES) *(uint4*)(Aw + off) = z4;
    }
    // scatter ones: dups overwrite (ref .at[].max()), idx<0 skipped
#pragma unroll
    for (int i = 0; i < 16; ++i) {
      int row = i * 2 + lh;
      int idx = isrc[(R + rgrp * 64 + t * 32 + row) * MAXA + l31];
      if (idx >= 0) Aw[row * ASTRIDE + idx] = 1;
    }
    // lift: lane supplies A[m=l31][k=lh*16+e], e=0..15
#pragma unroll
    for (int kc = 0; kc < KC; ++kc)
      areg[t][kc] = *(const v4i*)(Aw + l31 * ASTRIDE + kc * 32 + lh * 16);
  }

  // ---- park B-slab 0
#pragma unroll
  for (int s = 0; s < 6; ++s) ((uint4*)Bbuf[0])[s * 256 + tid] = st[s];
  __syncthreads();

  // ---- A maps dead: reuse Ash front 8 KB for this N-half's consts
  // [0,512) scale | [512,1024) bias | [1024,2048) outw (side-major halves)
  float* sbo = (float*)Ash;
  {
    const float4* g0 = (const float4*)(scale + nh * 512);
    const float4* g1 = (const float4*)(bias + nh * 512);
    const float4* g2 = (const float4*)(outw + nh * 512);
    const float4* g3 = (const float4*)(outw + HIDDEN + nh * 512);
    float4* d = (float4*)sbo;
    d[tid]       = (tid < 128) ? g0[tid] : g1[tid - 128];
    d[256 + tid] = (tid < 128) ? g2[tid] : g3[tid - 128];
  }
  __syncthreads();

  float prow0[16], prow1[16];
#pragma unroll
  for (int r = 0; r < 16; ++r) { prow0[r] = 0.f; prow1[r] = 0.f; }

#pragma unroll 1
  for (int nt = 0; nt < NTH; ++nt) {
    const int p = nt & 1;
    if (nt + 1 < NTH) {   // issue next slab (consumed after compute)
      const uint4* g = (const uint4*)(Bf + (size_t)(nh * NTH + nt + 1) * BTILE);
#pragma unroll
      for (int s = 0; s < 6; ++s) st[s] = g[s * 256 + tid];
    }
    v16i acc0, acc1;
#pragma unroll
    for (int r = 0; r < 16; ++r) { acc0[r] = 0; acc1[r] = 0; }
    const uint8_t* bp = Bbuf[p];
#pragma unroll
    for (int kc = 0; kc < KC; ++kc) {
      v4i b = *(const v4i*)(bp + kc * 1024 + lane * 16);
      acc0 = __builtin_amdgcn_mfma_i32_32x32x32_i8(areg[0][kc], b, acc0, 0, 0, 0);
      acc1 = __builtin_amdgcn_mfma_i32_32x32x32_i8(areg[1][kc], b, acc1, 0, 0, 0);
    }
    // epilogue: h = nh*512 + nt*32 + l31 (C col = lane&31)
    float s  = sbo[nt * 32 + l31];
    float bb = sbo[512 + nt * 32 + l31];
    float o  = sbo[1024 + side * 512 + nt * 32 + l31];
#pragma unroll
    for (int r = 0; r < 16; ++r) {
      float h0 = fminf(fmaxf(fmaf((float)acc0[r], s, bb), 0.f), 1.f);
      float h1 = fminf(fmaxf(fmaf((float)acc1[r], s, bb), 0.f), 1.f);
      prow0[r] = fmaf(h0, o, prow0[r]);
      prow1[r] = fmaf(h1, o, prow1[r]);
    }
    if (nt + 1 < NTH) {   // park next slab into the released buffer
      uint4* d = (uint4*)Bbuf[p ^ 1];
#pragma unroll
      for (int s2 = 0; s2 < 6; ++s2) d[s2 * 256 + tid] = st[s2];
    }
    __syncthreads();
  }

  // ---- reduce over the 32 h-columns (stay within each 32-lane half)
#pragma unroll
  for (int off = 16; off >= 1; off >>= 1)
#pragma unroll
    for (int r = 0; r < 16; ++r) {
      prow0[r] += __shfl_xor(prow0[r], off, 64);
      prow1[r] += __shfl_xor(prow1[r], off, 64);
    }

  if (l31 == 0) {
    // C row = (reg&3) + 8*(reg>>2) + 4*(lane>>5)  [HW-verified 32x32 layout]
#pragma unroll
    for (int r = 0; r < 16; ++r) {
      int crow = (r & 3) + 8 * (r >> 2) + 4 * lh;
      atomicAdd(&outz[R + rgrp * 64 + crow], prow0[r]);
      atomicAdd(&outz[R + rgrp * 64 + 32 + crow], prow1[r]);
    }
  }
}

// ---------------------------------------------------------------------------
// Final: sigmoid in place over the accumulated per-row dot.
// ---------------------------------------------------------------------------
__global__ __launch_bounds__(256) void nn_finish(float* __restrict__ outz,
                                                 const float* __restrict__ outb) {
  const int i = blockIdx.x * 256 + threadIdx.x;
  float y = outz[i] + outb[0];
  outz[i] = 1.f / (1.f + __expf(-y));
}

extern "C" void kernel_launch(void* const* d_in, const int* in_sizes, int n_in,
                              void* d_out, int out_size, void* d_ws, size_t ws_size,
                              hipStream_t stream) {
  const int*   stm  = (const int*)d_in[0];
  const int*   nstm = (const int*)d_in[1];
  const float* ftw  = (const float*)d_in[2];   // (1024, 768) fp32
  const float* ftb  = (const float*)d_in[3];   // (1024,) fp32
  const float* outw = (const float*)d_in[4];   // (2048,) fp32
  const float* outb = (const float*)d_in[5];   // (1,) fp32

  uint8_t* Bf    = (uint8_t*)d_ws;                        // 768 KiB fragments
  float*   scale = (float*)(Bf + (size_t)FEAT * HIDDEN);  // 4 KB
  float*   outz  = (float*)d_out;                         // accumulator + output

  prep_quant<<<HIDDEN / 8, 256, 0, stream>>>(ftw, Bf, scale, outz);
  nn_mfma<<<(BATCH / 128) * 2, 256, 0, stream>>>(stm, nstm, Bf, scale, ftb,
                                                 outw, outz);
  nn_finish<<<BATCH / 256, 256, 0, stream>>>(outz, outb);
}